// Round 11
// baseline (327.792 us; speedup 1.0000x reference)
//
#include <hip/hip_runtime.h>
#include <hip/hip_bf16.h>
#include <math.h>

#define Bb   4
#define Nn   2048
#define Dd   256
#define Hh   4
#define HDd  64
#define BN   (Bb * Nn)

typedef float v4f __attribute__((ext_vector_type(4)));
typedef short v8s __attribute__((ext_vector_type(8)));

__device__ __forceinline__ unsigned rne_bf16(float f) {
    unsigned u = __float_as_uint(f);
    u += 0x7fffu + ((u >> 16) & 1u);
    return u >> 16;
}

// ---------------------------------------------------------------------------
// Kernel 1: h = x @ W.T via MFMA, hi/lo bf16 split (err ~2^-17).
// Block = 256 thr (4 waves), C-tile 64m x 64n (n-tile == one head), grid 512.
// Epilogue: scores s_src/s_dst PRE-SCALED by log2(e), written TRANSPOSED
// [h][bn]; h -> bf16 TRANSPOSED-TILED hbf [b][jb(64)][hd(256)][j(32)]
// (== MFMA B-frag layout).
// ---------------------------------------------------------------------------
__global__ __launch_bounds__(256, 2) void k_gemm(const float* __restrict__ x,
                                                 const float* __restrict__ W,
                                                 const float* __restrict__ a_src,
                                                 const float* __restrict__ a_dst,
                                                 unsigned short* __restrict__ hbf,
                                                 float* __restrict__ ssrc,
                                                 float* __restrict__ sdst) {
    __shared__ __align__(16) unsigned short xs[2][64 * 72];  // hi, lo  (T reuses xs)
    __shared__ __align__(16) unsigned short wsm[2][64 * 72];
    __shared__ float asd[128];

    const int tid = threadIdx.x;
    const int m0 = (int)(blockIdx.x >> 2) * 64;
    const int head = (int)blockIdx.x & 3;
    const int n0 = head * 64;
    const int b = m0 >> 11;
    const int i0loc = m0 & 2047;

    if (tid < 128) {
        int sel = tid >> 6, d = tid & 63;
        asd[tid] = sel ? a_dst[n0 + d] : a_src[n0 + d];
    }

    const int wv = tid >> 6, ln = tid & 63, l15 = ln & 15, l4 = ln >> 4;
    const int mh = wv >> 1, nh = wv & 1;
    const int srow = tid >> 2, kq = (tid & 3) * 16;

    v4f acc[2][2];
#pragma unroll
    for (int g = 0; g < 2; ++g)
#pragma unroll
        for (int t = 0; t < 2; ++t) acc[g][t] = (v4f){0.f, 0.f, 0.f, 0.f};

    for (int st = 0; st < 4; ++st) {
        const int k0 = st * 64;
        __syncthreads();
        // ---- stage x and W tiles as bf16 hi/lo ----
        {
            float xf[16], wf[16];
            const float* xp = x + (size_t)(m0 + srow) * Dd + k0 + kq;
            const float* wp = W + (size_t)(n0 + srow) * Dd + k0 + kq;
#pragma unroll
            for (int q = 0; q < 4; ++q) {
                *(float4*)&xf[q * 4] = *(const float4*)(xp + q * 4);
                *(float4*)&wf[q * 4] = *(const float4*)(wp + q * 4);
            }
            unsigned xh[8], xl[8], wh[8], wl[8];
#pragma unroll
            for (int j = 0; j < 8; ++j) {
                unsigned h0 = rne_bf16(xf[2 * j]), h1 = rne_bf16(xf[2 * j + 1]);
                float l0 = xf[2 * j] - __uint_as_float(h0 << 16);
                float l1 = xf[2 * j + 1] - __uint_as_float(h1 << 16);
                xh[j] = h0 | (h1 << 16);
                xl[j] = rne_bf16(l0) | (rne_bf16(l1) << 16);
                unsigned g0 = rne_bf16(wf[2 * j]), g1 = rne_bf16(wf[2 * j + 1]);
                float m0f = wf[2 * j] - __uint_as_float(g0 << 16);
                float m1f = wf[2 * j + 1] - __uint_as_float(g1 << 16);
                wh[j] = g0 | (g1 << 16);
                wl[j] = rne_bf16(m0f) | (rne_bf16(m1f) << 16);
            }
            *(uint4*)(xs[0] + srow * 72 + kq)     = make_uint4(xh[0], xh[1], xh[2], xh[3]);
            *(uint4*)(xs[0] + srow * 72 + kq + 8) = make_uint4(xh[4], xh[5], xh[6], xh[7]);
            *(uint4*)(xs[1] + srow * 72 + kq)     = make_uint4(xl[0], xl[1], xl[2], xl[3]);
            *(uint4*)(xs[1] + srow * 72 + kq + 8) = make_uint4(xl[4], xl[5], xl[6], xl[7]);
            *(uint4*)(wsm[0] + srow * 72 + kq)     = make_uint4(wh[0], wh[1], wh[2], wh[3]);
            *(uint4*)(wsm[0] + srow * 72 + kq + 8) = make_uint4(wh[4], wh[5], wh[6], wh[7]);
            *(uint4*)(wsm[1] + srow * 72 + kq)     = make_uint4(wl[0], wl[1], wl[2], wl[3]);
            *(uint4*)(wsm[1] + srow * 72 + kq + 8) = make_uint4(wl[4], wl[5], wl[6], wl[7]);
        }
        __syncthreads();
        // ---- MFMA: wave (mh, nh) owns 2x2 16-tiles ----
        {
            v8s ah[2][2], al[2][2], bh_[2][2], bl_[2][2];
#pragma unroll
            for (int g = 0; g < 2; ++g)
#pragma unroll
                for (int kh = 0; kh < 2; ++kh) {
                    int ro = (mh * 32 + g * 16 + l15) * 72 + kh * 32 + l4 * 8;
                    ah[g][kh] = *(const v8s*)(xs[0] + ro);
                    al[g][kh] = *(const v8s*)(xs[1] + ro);
                }
#pragma unroll
            for (int t = 0; t < 2; ++t)
#pragma unroll
                for (int kh = 0; kh < 2; ++kh) {
                    int ro = (nh * 32 + t * 16 + l15) * 72 + kh * 32 + l4 * 8;
                    bh_[t][kh] = *(const v8s*)(wsm[0] + ro);
                    bl_[t][kh] = *(const v8s*)(wsm[1] + ro);
                }
#pragma unroll
            for (int g = 0; g < 2; ++g)
#pragma unroll
                for (int t = 0; t < 2; ++t)
#pragma unroll
                    for (int kh = 0; kh < 2; ++kh) {
                        acc[g][t] = __builtin_amdgcn_mfma_f32_16x16x32_bf16(ah[g][kh], bh_[t][kh], acc[g][t], 0, 0, 0);
                        acc[g][t] = __builtin_amdgcn_mfma_f32_16x16x32_bf16(al[g][kh], bh_[t][kh], acc[g][t], 0, 0, 0);
                        acc[g][t] = __builtin_amdgcn_mfma_f32_16x16x32_bf16(ah[g][kh], bl_[t][kh], acc[g][t], 0, 0, 0);
                    }
        }
    }

    // ---- epilogue: C -> T[d][m] (stride 67) ----
    __syncthreads();
    float* T = (float*)&xs[0][0];   // 64*67*4 = 17168 B
#pragma unroll
    for (int g = 0; g < 2; ++g)
#pragma unroll
        for (int t = 0; t < 2; ++t)
#pragma unroll
            for (int r = 0; r < 4; ++r) {
                int d = nh * 32 + t * 16 + l15;
                int m = mh * 32 + g * 16 + l4 * 4 + r;
                T[d * 67 + m] = acc[g][t][r];
            }
    __syncthreads();
    if (tid < 128) {
        // scores -> TRANSPOSED [h][bn], PRE-SCALED by log2(e) for v_exp
        int m = tid & 63, sel = tid >> 6;
        float s = 0.f;
#pragma unroll
        for (int d = 0; d < 64; ++d) s += T[d * 67 + m] * asd[sel * 64 + d];
        (sel ? sdst : ssrc)[(size_t)head * BN + (size_t)b * Nn + i0loc + m] =
            s * 1.4426950408889634f;
        // hbf pack
        int dloc = tid >> 1, jh = tid & 1;
        const float* row = T + dloc * 67 + jh * 32;
        unsigned pk[16];
#pragma unroll
        for (int jj = 0; jj < 16; ++jj)
            pk[jj] = rne_bf16(row[jj * 2]) | (rne_bf16(row[jj * 2 + 1]) << 16);
        unsigned short* dst = hbf +
            ((size_t)((b * 64 + (i0loc >> 5) + jh) * 256 + head * HDd + dloc)) * 32;
        uint4* d4 = (uint4*)dst;
        d4[0] = make_uint4(pk[0], pk[1], pk[2], pk[3]);
        d4[1] = make_uint4(pk[4], pk[5], pk[6], pk[7]);
        d4[2] = make_uint4(pk[8], pk[9], pk[10], pk[11]);
        d4[3] = make_uint4(pk[12], pk[13], pk[14], pk[15]);
    }
}

// ---------------------------------------------------------------------------
// Kernel 2: wave-autonomous MFMA softmax-aggregate, D-SPLIT for TLP.
// Wave = (b, i-tile 16, head, d-quarter) -> 8192 waves (4x R9), grid 2048
// blocks x 256 thr; block = the 4 d-quarters of one (b,i16,h) so the
// re-generated w~ reads the same adj lines (L1-resident, 2 KB/step).
// No LDS / barriers / atomics / partial buffers: each wave MFMAs only its
// 16-d slice (1 acc + 1 Z MFMA per step) and stores exclusively.
// Rings depth-2 (the scheduling R9's compiler respected); VGPR capped for
// >=6 waves/SIMD (24 waves/CU). h in high bid bits -> the 4 h-blocks of one
// (b,i16) share bid mod 8 (same XCD L2) for adj reuse.
// ---------------------------------------------------------------------------
__global__ __launch_bounds__(256, 6) void k_aggr(const unsigned short* __restrict__ hbf,
                                                 const float* __restrict__ adj,
                                                 const float* __restrict__ ssrc,
                                                 const float* __restrict__ sdst,
                                                 float* __restrict__ out) {
    const int tid = threadIdx.x;
    const int tl = tid >> 6;                      // wave in block = d-quarter
    const int bid = (int)blockIdx.x;
    const int h = bid >> 9;                       // 0..3
    const int lin = bid & 511;
    const int b = lin >> 7;
    const int i0 = (lin & 127) * 16;
    const int ln = tid & 63, l15 = ln & 15, l4 = ln >> 4;

    const float ssv = ssrc[(size_t)h * BN + (size_t)b * Nn + i0 + l15];  // pre-scaled
    const float* adjr = adj + (size_t)b * Nn * Nn + (size_t)(i0 + l15) * Nn + l4 * 8;
    const float* sdr  = sdst + (size_t)h * BN + (size_t)b * Nn + l4 * 8;
    const unsigned short* hrow = hbf +
        ((size_t)(b * 64) * 256 + (size_t)(h * HDd + tl * 16 + l15)) * 32 + l4 * 8;

    const v8s ones = {0x3F80, 0x3F80, 0x3F80, 0x3F80, 0x3F80, 0x3F80, 0x3F80, 0x3F80};

    v4f acc = (v4f){0.f, 0.f, 0.f, 0.f};
    v4f zac = (v4f){0.f, 0.f, 0.f, 0.f};

    // ---- depth-2 prefetch rings ----
    float4 ajA[2], ajB[2], sdA[2], sdB[2];
    v8s bfr[2];
#pragma unroll
    for (int p = 0; p < 2; ++p) {
        ajA[p] = *(const float4*)(adjr + p * 32);
        ajB[p] = *(const float4*)(adjr + p * 32 + 4);
        sdA[p] = *(const float4*)(sdr + p * 32);
        sdB[p] = *(const float4*)(sdr + p * 32 + 4);
        bfr[p] = *(const v8s*)(hrow + (size_t)p * 8192);
    }

#pragma unroll 2
    for (int st = 0; st < 64; ++st) {
        const int c = st & 1;
        // ---- build a-frag in registers from ring[c] ----
        union { v8s v; unsigned u[4]; } A;
        {
            const float aj8[8] = {ajA[c].x, ajA[c].y, ajA[c].z, ajA[c].w,
                                  ajB[c].x, ajB[c].y, ajB[c].z, ajB[c].w};
            const float sd8[8] = {sdA[c].x, sdA[c].y, sdA[c].z, sdA[c].w,
                                  sdB[c].x, sdB[c].y, sdB[c].z, sdB[c].w};
#pragma unroll
            for (int p = 0; p < 4; ++p) {
                float e0 = ssv + sd8[2 * p];
                float e1 = ssv + sd8[2 * p + 1];
                e0 = fmaxf(e0, 0.2f * e0);
                e1 = fmaxf(e1, 0.2f * e1);
                float w0 = aj8[2 * p] * __builtin_amdgcn_exp2f(e0);
                float w1 = aj8[2 * p + 1] * __builtin_amdgcn_exp2f(e1);
                __hip_bfloat162 pk2 = __float22bfloat162_rn(make_float2(w0, w1));
                A.u[p] = *reinterpret_cast<unsigned*>(&pk2);
            }
        }
        // ---- snapshot current B; refill ring slot c with step st+2 ----
        v8s bcur = bfr[c];
        {
            const int s2 = (st + 2) & 63;
            bfr[c] = *(const v8s*)(hrow + (size_t)s2 * 8192);
            ajA[c] = *(const float4*)(adjr + s2 * 32);
            ajB[c] = *(const float4*)(adjr + s2 * 32 + 4);
            sdA[c] = *(const float4*)(sdr + s2 * 32);
            sdB[c] = *(const float4*)(sdr + s2 * 32 + 4);
        }
        // ---- MFMA: this wave's 16-d slice + Z ----
        acc = __builtin_amdgcn_mfma_f32_16x16x32_bf16(A.v, bcur, acc, 0, 0, 0);
        zac = __builtin_amdgcn_mfma_f32_16x16x32_bf16(A.v, ones, zac, 0, 0, 0);
    }

    // ---- epilogue: register-local normalize + exclusive store ----
    const int d = h * HDd + tl * 16 + l15;
#pragma unroll
    for (int r = 0; r < 4; ++r) {
        float zinv = 1.f / zac[r];
        int i = i0 + l4 * 4 + r;
        out[((size_t)b * Nn + i) * Dd + d] = acc[r] * zinv;
    }
}

extern "C" void kernel_launch(void* const* d_in, const int* in_sizes, int n_in,
                              void* d_out, int out_size, void* d_ws, size_t ws_size,
                              hipStream_t stream) {
    const float* x     = (const float*)d_in[0];
    const float* adj   = (const float*)d_in[1];
    const float* W     = (const float*)d_in[2];
    const float* a_src = (const float*)d_in[3];
    const float* a_dst = (const float*)d_in[4];
    float* out = (float*)d_out;

    // ws: hbf 4MB | ssrc [h][bn] 128KB | sdst [h][bn] 128KB
    unsigned short* hbf = (unsigned short*)d_ws;
    float* ssrc = (float*)(hbf + (size_t)Bb * Nn * Dd);
    float* sdst = ssrc + (size_t)Hh * BN;

    k_gemm<<<dim3(512), dim3(256), 0, stream>>>(x, W, a_src, a_dst, hbf, ssrc, sdst);
    k_aggr<<<dim3(2048), dim3(256), 0, stream>>>(hbf, adj, ssrc, sdst, out);
}

// Round 12
// 165.031 us; speedup vs baseline: 1.9862x; 1.9862x over previous
//
#include <hip/hip_runtime.h>
#include <hip/hip_bf16.h>
#include <math.h>

#define Bb   4
#define Nn   2048
#define Dd   256
#define Hh   4
#define HDd  64
#define BN   (Bb * Nn)

typedef float v4f __attribute__((ext_vector_type(4)));
typedef short v8s __attribute__((ext_vector_type(8)));

__device__ __forceinline__ unsigned rne_bf16(float f) {
    unsigned u = __float_as_uint(f);
    u += 0x7fffu + ((u >> 16) & 1u);
    return u >> 16;
}

// ---------------------------------------------------------------------------
// Kernel 1: h = x @ W.T via MFMA, hi/lo bf16 split (err ~2^-17).
// Block = 256 thr (4 waves), C-tile 64m x 64n (n-tile == one head), grid 512.
// Epilogue: scores s_src/s_dst PRE-SCALED by log2(e), written TRANSPOSED
// [h][bn]; h -> bf16 TRANSPOSED-TILED hbf [b][jb(64)][hd(256)][j(32)]
// (== MFMA B-frag layout).
// ---------------------------------------------------------------------------
__global__ __launch_bounds__(256, 2) void k_gemm(const float* __restrict__ x,
                                                 const float* __restrict__ W,
                                                 const float* __restrict__ a_src,
                                                 const float* __restrict__ a_dst,
                                                 unsigned short* __restrict__ hbf,
                                                 float* __restrict__ ssrc,
                                                 float* __restrict__ sdst) {
    __shared__ __align__(16) unsigned short xs[2][64 * 72];  // hi, lo  (T reuses xs)
    __shared__ __align__(16) unsigned short wsm[2][64 * 72];
    __shared__ float asd[128];

    const int tid = threadIdx.x;
    const int m0 = (int)(blockIdx.x >> 2) * 64;
    const int head = (int)blockIdx.x & 3;
    const int n0 = head * 64;
    const int b = m0 >> 11;
    const int i0loc = m0 & 2047;

    if (tid < 128) {
        int sel = tid >> 6, d = tid & 63;
        asd[tid] = sel ? a_dst[n0 + d] : a_src[n0 + d];
    }

    const int wv = tid >> 6, ln = tid & 63, l15 = ln & 15, l4 = ln >> 4;
    const int mh = wv >> 1, nh = wv & 1;
    const int srow = tid >> 2, kq = (tid & 3) * 16;

    v4f acc[2][2];
#pragma unroll
    for (int g = 0; g < 2; ++g)
#pragma unroll
        for (int t = 0; t < 2; ++t) acc[g][t] = (v4f){0.f, 0.f, 0.f, 0.f};

    for (int st = 0; st < 4; ++st) {
        const int k0 = st * 64;
        __syncthreads();
        // ---- stage x and W tiles as bf16 hi/lo ----
        {
            float xf[16], wf[16];
            const float* xp = x + (size_t)(m0 + srow) * Dd + k0 + kq;
            const float* wp = W + (size_t)(n0 + srow) * Dd + k0 + kq;
#pragma unroll
            for (int q = 0; q < 4; ++q) {
                *(float4*)&xf[q * 4] = *(const float4*)(xp + q * 4);
                *(float4*)&wf[q * 4] = *(const float4*)(wp + q * 4);
            }
            unsigned xh[8], xl[8], wh[8], wl[8];
#pragma unroll
            for (int j = 0; j < 8; ++j) {
                unsigned h0 = rne_bf16(xf[2 * j]), h1 = rne_bf16(xf[2 * j + 1]);
                float l0 = xf[2 * j] - __uint_as_float(h0 << 16);
                float l1 = xf[2 * j + 1] - __uint_as_float(h1 << 16);
                xh[j] = h0 | (h1 << 16);
                xl[j] = rne_bf16(l0) | (rne_bf16(l1) << 16);
                unsigned g0 = rne_bf16(wf[2 * j]), g1 = rne_bf16(wf[2 * j + 1]);
                float m0f = wf[2 * j] - __uint_as_float(g0 << 16);
                float m1f = wf[2 * j + 1] - __uint_as_float(g1 << 16);
                wh[j] = g0 | (g1 << 16);
                wl[j] = rne_bf16(m0f) | (rne_bf16(m1f) << 16);
            }
            *(uint4*)(xs[0] + srow * 72 + kq)     = make_uint4(xh[0], xh[1], xh[2], xh[3]);
            *(uint4*)(xs[0] + srow * 72 + kq + 8) = make_uint4(xh[4], xh[5], xh[6], xh[7]);
            *(uint4*)(xs[1] + srow * 72 + kq)     = make_uint4(xl[0], xl[1], xl[2], xl[3]);
            *(uint4*)(xs[1] + srow * 72 + kq + 8) = make_uint4(xl[4], xl[5], xl[6], xl[7]);
            *(uint4*)(wsm[0] + srow * 72 + kq)     = make_uint4(wh[0], wh[1], wh[2], wh[3]);
            *(uint4*)(wsm[0] + srow * 72 + kq + 8) = make_uint4(wh[4], wh[5], wh[6], wh[7]);
            *(uint4*)(wsm[1] + srow * 72 + kq)     = make_uint4(wl[0], wl[1], wl[2], wl[3]);
            *(uint4*)(wsm[1] + srow * 72 + kq + 8) = make_uint4(wl[4], wl[5], wl[6], wl[7]);
        }
        __syncthreads();
        // ---- MFMA: wave (mh, nh) owns 2x2 16-tiles ----
        {
            v8s ah[2][2], al[2][2], bh_[2][2], bl_[2][2];
#pragma unroll
            for (int g = 0; g < 2; ++g)
#pragma unroll
                for (int kh = 0; kh < 2; ++kh) {
                    int ro = (mh * 32 + g * 16 + l15) * 72 + kh * 32 + l4 * 8;
                    ah[g][kh] = *(const v8s*)(xs[0] + ro);
                    al[g][kh] = *(const v8s*)(xs[1] + ro);
                }
#pragma unroll
            for (int t = 0; t < 2; ++t)
#pragma unroll
                for (int kh = 0; kh < 2; ++kh) {
                    int ro = (nh * 32 + t * 16 + l15) * 72 + kh * 32 + l4 * 8;
                    bh_[t][kh] = *(const v8s*)(wsm[0] + ro);
                    bl_[t][kh] = *(const v8s*)(wsm[1] + ro);
                }
#pragma unroll
            for (int g = 0; g < 2; ++g)
#pragma unroll
                for (int t = 0; t < 2; ++t)
#pragma unroll
                    for (int kh = 0; kh < 2; ++kh) {
                        acc[g][t] = __builtin_amdgcn_mfma_f32_16x16x32_bf16(ah[g][kh], bh_[t][kh], acc[g][t], 0, 0, 0);
                        acc[g][t] = __builtin_amdgcn_mfma_f32_16x16x32_bf16(al[g][kh], bh_[t][kh], acc[g][t], 0, 0, 0);
                        acc[g][t] = __builtin_amdgcn_mfma_f32_16x16x32_bf16(ah[g][kh], bl_[t][kh], acc[g][t], 0, 0, 0);
                    }
        }
    }

    // ---- epilogue: C -> T[d][m] (stride 67) ----
    __syncthreads();
    float* T = (float*)&xs[0][0];   // 64*67*4 = 17168 B
#pragma unroll
    for (int g = 0; g < 2; ++g)
#pragma unroll
        for (int t = 0; t < 2; ++t)
#pragma unroll
            for (int r = 0; r < 4; ++r) {
                int d = nh * 32 + t * 16 + l15;
                int m = mh * 32 + g * 16 + l4 * 4 + r;
                T[d * 67 + m] = acc[g][t][r];
            }
    __syncthreads();
    if (tid < 128) {
        // scores -> TRANSPOSED [h][bn], PRE-SCALED by log2(e) for v_exp
        int m = tid & 63, sel = tid >> 6;
        float s = 0.f;
#pragma unroll
        for (int d = 0; d < 64; ++d) s += T[d * 67 + m] * asd[sel * 64 + d];
        (sel ? sdst : ssrc)[(size_t)head * BN + (size_t)b * Nn + i0loc + m] =
            s * 1.4426950408889634f;
        // hbf pack
        int dloc = tid >> 1, jh = tid & 1;
        const float* row = T + dloc * 67 + jh * 32;
        unsigned pk[16];
#pragma unroll
        for (int jj = 0; jj < 16; ++jj)
            pk[jj] = rne_bf16(row[jj * 2]) | (rne_bf16(row[jj * 2 + 1]) << 16);
        unsigned short* dst = hbf +
            ((size_t)((b * 64 + (i0loc >> 5) + jh) * 256 + head * HDd + dloc)) * 32;
        uint4* d4 = (uint4*)dst;
        d4[0] = make_uint4(pk[0], pk[1], pk[2], pk[3]);
        d4[1] = make_uint4(pk[4], pk[5], pk[6], pk[7]);
        d4[2] = make_uint4(pk[8], pk[9], pk[10], pk[11]);
        d4[3] = make_uint4(pk[12], pk[13], pk[14], pk[15]);
    }
}

// ---------------------------------------------------------------------------
// Kernel 2: MFMA softmax-aggregate, R8 flow + 4 blocks/CU for stall cover.
// Block = 512 thr (8 waves) <-> (b, i-tile 16, head-pair); grid 1024
// -> 4 blocks/CU, 32 waves/CU. Single barrier/step, Aw dbuf (9.2 KB),
// B-frags DIRECT from hbf (B-frag layout, 1KB coalesced loads), Z via
// ones-MFMA, exp2-prescaled scores, packed bf16 cvt. hp pairs share
// bid%8 (same XCD L2) for adj reuse. VGPR capped for 8 waves/SIMD.
// ---------------------------------------------------------------------------
__global__ __launch_bounds__(512, 8) void k_aggr(const unsigned short* __restrict__ hbf,
                                                 const float* __restrict__ adj,
                                                 const float* __restrict__ ssrc,
                                                 const float* __restrict__ sdst,
                                                 float* __restrict__ out) {
    __shared__ __align__(16) unsigned short Aw[2][32 * 72];   // dbuf, 9.2 KB

    const int tid = threadIdx.x;
    const int bid = (int)blockIdx.x;
    const int hp  = (bid >> 3) & 1;                  // head pair
    const int lin = (bid & 7) | ((bid >> 4) << 3);   // XCD-paired (b, i-tile)
    const int b  = lin >> 7;
    const int i0 = (lin & 127) * 16;

    // gen: thread = (gi 0..15, jq 0..31) -> 2 j x 2 heads
    const int gi = tid >> 5, jq = tid & 31;
    // mfma: wave = (hl, tl d-quarter)
    const int wv = tid >> 6;
    const int hl = wv >> 2, tl = wv & 3;
    const int ln = tid & 63, l15 = ln & 15, l4 = ln >> 4;

    const float ss0 = ssrc[(size_t)(hp * 2 + 0) * BN + (size_t)b * Nn + i0 + gi];
    const float ss1 = ssrc[(size_t)(hp * 2 + 1) * BN + (size_t)b * Nn + i0 + gi];
    const float* adjr = adj + (size_t)b * Nn * Nn + (size_t)(i0 + gi) * Nn;
    const float* sdr0 = sdst + (size_t)(hp * 2 + 0) * BN + (size_t)b * Nn;
    const float* sdr1 = sdst + (size_t)(hp * 2 + 1) * BN + (size_t)b * Nn;

    // B-frag row pointer (hbf is already in B-fragment layout)
    const unsigned short* hrow = hbf +
        ((size_t)(b * 64) * 256 + (size_t)(hp * 128 + hl * 64 + tl * 16 + l15)) * 32 + l4 * 8;

    const v8s ones = {0x3F80, 0x3F80, 0x3F80, 0x3F80, 0x3F80, 0x3F80, 0x3F80, 0x3F80};

    v4f acc = (v4f){0.f, 0.f, 0.f, 0.f};
    v4f zac = (v4f){0.f, 0.f, 0.f, 0.f};

    // prefetch step 0
    float2 aj = *(const float2*)(adjr + jq * 2);
    float2 s0 = *(const float2*)(sdr0 + jq * 2);
    float2 s1 = *(const float2*)(sdr1 + jq * 2);

#pragma unroll 2
    for (int st = 0; st < 32; ++st) {
        const int c = st & 1;
        // ---- gen 2 j x 2 heads from pf regs into Aw[c] ----
        {
            float e00 = ss0 + s0.x, e01 = ss0 + s0.y;
            float e10 = ss1 + s1.x, e11 = ss1 + s1.y;
            e00 = fmaxf(e00, 0.2f * e00); e01 = fmaxf(e01, 0.2f * e01);
            e10 = fmaxf(e10, 0.2f * e10); e11 = fmaxf(e11, 0.2f * e11);
            float w00 = aj.x * __builtin_amdgcn_exp2f(e00);
            float w01 = aj.y * __builtin_amdgcn_exp2f(e01);
            float w10 = aj.x * __builtin_amdgcn_exp2f(e10);
            float w11 = aj.y * __builtin_amdgcn_exp2f(e11);
            __hip_bfloat162 p0 = __float22bfloat162_rn(make_float2(w00, w01));
            __hip_bfloat162 p1 = __float22bfloat162_rn(make_float2(w10, w11));
            *(unsigned*)(Aw[c] + gi * 72 + jq * 2)        = *reinterpret_cast<unsigned*>(&p0);
            *(unsigned*)(Aw[c] + (16 + gi) * 72 + jq * 2) = *reinterpret_cast<unsigned*>(&p1);
        }
        __syncthreads();
        // ---- prefetch next step (covered by MFMA below + other blocks) ----
        {
            const int jn = ((st + 1) & 31) * 64;
            aj = *(const float2*)(adjr + jn + jq * 2);
            s0 = *(const float2*)(sdr0 + jn + jq * 2);
            s1 = *(const float2*)(sdr1 + jn + jq * 2);
        }
        // ---- MFMA: A from Aw[c], B direct from global (L2) ----
        {
            const unsigned short* awp = Aw[c] + (hl * 16 + l15) * 72 + l4 * 8;
            v8s a0 = *(const v8s*)(awp);
            v8s a1 = *(const v8s*)(awp + 32);
            v8s b0 = *(const v8s*)(hrow + (size_t)(2 * st + 0) * 8192);
            v8s b1 = *(const v8s*)(hrow + (size_t)(2 * st + 1) * 8192);
            acc = __builtin_amdgcn_mfma_f32_16x16x32_bf16(a0, b0, acc, 0, 0, 0);
            acc = __builtin_amdgcn_mfma_f32_16x16x32_bf16(a1, b1, acc, 0, 0, 0);
            zac = __builtin_amdgcn_mfma_f32_16x16x32_bf16(a0, ones, zac, 0, 0, 0);
            zac = __builtin_amdgcn_mfma_f32_16x16x32_bf16(a1, ones, zac, 0, 0, 0);
        }
    }

    // ---- epilogue: register-local normalize + exclusive store ----
    const int head = hp * 2 + hl;
    const int d = head * HDd + tl * 16 + l15;
#pragma unroll
    for (int r = 0; r < 4; ++r) {
        float zinv = 1.f / zac[r];
        int i = i0 + l4 * 4 + r;
        out[((size_t)b * Nn + i) * Dd + d] = acc[r] * zinv;
    }
}

extern "C" void kernel_launch(void* const* d_in, const int* in_sizes, int n_in,
                              void* d_out, int out_size, void* d_ws, size_t ws_size,
                              hipStream_t stream) {
    const float* x     = (const float*)d_in[0];
    const float* adj   = (const float*)d_in[1];
    const float* W     = (const float*)d_in[2];
    const float* a_src = (const float*)d_in[3];
    const float* a_dst = (const float*)d_in[4];
    float* out = (float*)d_out;

    // ws: hbf 4MB | ssrc [h][bn] 128KB | sdst [h][bn] 128KB
    unsigned short* hbf = (unsigned short*)d_ws;
    float* ssrc = (float*)(hbf + (size_t)Bb * Nn * Dd);
    float* sdst = ssrc + (size_t)Hh * BN;

    k_gemm<<<dim3(512), dim3(256), 0, stream>>>(x, W, a_src, a_dst, hbf, ssrc, sdst);
    k_aggr<<<dim3(1024), dim3(512), 0, stream>>>(hbf, adj, ssrc, sdst, out);
}